// Round 1
// baseline (817.942 us; speedup 1.0000x reference)
//
#include <hip/hip_runtime.h>
#include <hip/hip_bf16.h>

#define B_  32
#define N_  2048
#define M_  2048
#define D_  128

typedef __attribute__((ext_vector_type(4))) float f32x4;
typedef __attribute__((ext_vector_type(8))) short bf16x8;

// log2(e) / sqrt(128): do softmax in exp2 domain (v_exp_f32 is exp2)
static constexpr float SCALE2 = 1.4426950408889634f / 11.313708498984761f;

__device__ __forceinline__ unsigned short f2bf(float x) {
  union { float f; unsigned u; } c; c.f = x;
  unsigned u = c.u;
  return (unsigned short)((u + 0x7FFFu + ((u >> 16) & 1u)) >> 16);  // RNE
}

// ---------- prep: fp32 -> bf16 elementwise (for Q and K) ----------
__global__ __launch_bounds__(256) void cvt_bf16_kernel(
    const float* __restrict__ src, unsigned short* __restrict__ dst, int n4) {
  int i = blockIdx.x * blockDim.x + threadIdx.x;
  if (i >= n4) return;
  const float4 v = reinterpret_cast<const float4*>(src)[i];
  ushort4 o;
  o.x = f2bf(v.x); o.y = f2bf(v.y); o.z = f2bf(v.z); o.w = f2bf(v.w);
  reinterpret_cast<ushort4*>(dst)[i] = o;
}

// ---------- prep: V (b,m,d) fp32 -> Vt (b,d,m) bf16, tiled transpose ----------
__global__ __launch_bounds__(256) void transpose_v_kernel(
    const float* __restrict__ V, unsigned short* __restrict__ Vt) {
  const int b = blockIdx.z;
  const int m0 = blockIdx.x * 64;
  const int d0 = blockIdx.y * 64;
  __shared__ float t[64][65];
  const int tid = threadIdx.x;
  const int r = tid >> 2;   // 0..63
  const int c = tid & 3;    // 0..3
  const float* src = V + ((size_t)b * M_ + (m0 + r)) * D_ + d0 + c * 16;
  #pragma unroll
  for (int i = 0; i < 4; ++i) {
    float4 v = reinterpret_cast<const float4*>(src)[i];
    t[r][c * 16 + i * 4 + 0] = v.x;
    t[r][c * 16 + i * 4 + 1] = v.y;
    t[r][c * 16 + i * 4 + 2] = v.z;
    t[r][c * 16 + i * 4 + 3] = v.w;
  }
  __syncthreads();
  // now r = d-row within tile, c = m-group of 16
  ushort4 ob[4];
  #pragma unroll
  for (int i = 0; i < 4; ++i) {
    ob[i].x = f2bf(t[c * 16 + i * 4 + 0][r]);
    ob[i].y = f2bf(t[c * 16 + i * 4 + 1][r]);
    ob[i].z = f2bf(t[c * 16 + i * 4 + 2][r]);
    ob[i].w = f2bf(t[c * 16 + i * 4 + 3][r]);
  }
  ushort4* dst = reinterpret_cast<ushort4*>(
      Vt + ((size_t)b * D_ + d0 + r) * M_ + m0 + c * 16);
  #pragma unroll
  for (int i = 0; i < 4; ++i) dst[i] = ob[i];
}

// ---------- pass 1: per-column (m) stats over n: cmla = colmax2 + log2(colsum) ----------
// grid (M/64, B), block 256 = 4 waves; wave owns 16 columns, loops all n in 16-row tiles.
__global__ __launch_bounds__(256) void colstats_kernel(
    const unsigned short* __restrict__ Qb, const unsigned short* __restrict__ Kb,
    float* __restrict__ cmla) {
  const int b    = blockIdx.y;
  const int wv   = threadIdx.x >> 6;
  const int lane = threadIdx.x & 63;
  const int mcol = lane & 15;
  const int quad = lane >> 4;
  const int m = blockIdx.x * 64 + wv * 16 + mcol;

  // K fragments (B-operand: B[m=lane&15][k=quad*8+j]) — loop invariant, keep in regs
  const unsigned short* Krow = Kb + ((size_t)b * M_ + m) * D_ + quad * 8;
  bf16x8 kf[4];
  #pragma unroll
  for (int kc = 0; kc < 4; ++kc)
    kf[kc] = *reinterpret_cast<const bf16x8*>(Krow + kc * 32);

  const unsigned short* Qbase =
      Qb + ((size_t)b * N_ + mcol) * D_ + quad * 8;  // lane&15 = n-row within tile

  float rmax = -1e30f, rsum = 0.f;
  for (int nt = 0; nt < N_; nt += 16) {
    const unsigned short* Qp = Qbase + (size_t)nt * D_;
    f32x4 acc = {0.f, 0.f, 0.f, 0.f};
    #pragma unroll
    for (int kc = 0; kc < 4; ++kc) {
      bf16x8 af = *reinterpret_cast<const bf16x8*>(Qp + kc * 32);
      acc = __builtin_amdgcn_mfma_f32_16x16x32_bf16(af, kf[kc], acc, 0, 0, 0);
    }
    // acc[r] = s_raw[n = nt + quad*4 + r][m], scale into log2 domain
    float s0 = acc[0] * SCALE2, s1 = acc[1] * SCALE2;
    float s2 = acc[2] * SCALE2, s3 = acc[3] * SCALE2;
    float tmax = fmaxf(fmaxf(s0, s1), fmaxf(s2, s3));
    tmax = fmaxf(tmax, __shfl_xor(tmax, 16));
    tmax = fmaxf(tmax, __shfl_xor(tmax, 32));
    float tsum = exp2f(s0 - tmax) + exp2f(s1 - tmax) +
                 exp2f(s2 - tmax) + exp2f(s3 - tmax);
    tsum += __shfl_xor(tsum, 16);
    tsum += __shfl_xor(tsum, 32);
    float nm = fmaxf(rmax, tmax);
    rsum = rsum * exp2f(rmax - nm) + tsum * exp2f(tmax - nm);
    rmax = nm;
  }
  if (quad == 0) cmla[(size_t)b * M_ + m] = rmax + log2f(rsum);
}

// ---------- pass 2: O[n,d] = sum_m exp2(s2 - cmla[m]) * V[m,d] ----------
// grid (N/64, B), block 256 = 4 waves; wave owns 16 n-rows, loops m in 32-col chunks.
__global__ __launch_bounds__(256) void attn_out_kernel(
    const unsigned short* __restrict__ Qb, const unsigned short* __restrict__ Kb,
    const unsigned short* __restrict__ Vt, const float* __restrict__ cmla,
    float* __restrict__ out) {
  const int b    = blockIdx.y;
  const int wv   = threadIdx.x >> 6;
  const int lane = threadIdx.x & 63;
  const int mcol = lane & 15;
  const int quad = lane >> 4;
  const int n0 = blockIdx.x * 64 + wv * 16;

  __shared__ float cm[M_];                     // 8 KB: cmla row for this batch
  __shared__ unsigned short wbuf[4][16][32];   // 4 KB: per-wave P-tile relayout

  for (int i = threadIdx.x; i < M_; i += 256)
    cm[i] = cmla[(size_t)b * M_ + i];
  __syncthreads();

  // Q fragments (A-operand: A[n=lane&15][k=quad*8+j]) — loop invariant
  const unsigned short* Qrow = Qb + ((size_t)b * N_ + n0 + mcol) * D_ + quad * 8;
  bf16x8 qf[4];
  #pragma unroll
  for (int kc = 0; kc < 4; ++kc)
    qf[kc] = *reinterpret_cast<const bf16x8*>(Qrow + kc * 32);

  f32x4 o[8];
  #pragma unroll
  for (int dt = 0; dt < 8; ++dt) o[dt] = (f32x4){0.f, 0.f, 0.f, 0.f};

  const unsigned short* Kbase = Kb + (size_t)b * M_ * D_;
  const unsigned short* Vbase = Vt + (size_t)b * D_ * M_;

  for (int m0 = 0; m0 < M_; m0 += 32) {
    #pragma unroll
    for (int cg = 0; cg < 2; ++cg) {
      const unsigned short* Kp =
          Kbase + (size_t)(m0 + cg * 16 + mcol) * D_ + quad * 8;
      f32x4 s = {0.f, 0.f, 0.f, 0.f};
      #pragma unroll
      for (int kc = 0; kc < 4; ++kc) {
        bf16x8 bfK = *reinterpret_cast<const bf16x8*>(Kp + kc * 32);
        s = __builtin_amdgcn_mfma_f32_16x16x32_bf16(qf[kc], bfK, s, 0, 0, 0);
      }
      // s[r]: row n0+quad*4+r, col m0+cg*16+mcol
      float c = cm[m0 + cg * 16 + mcol];
      #pragma unroll
      for (int r = 0; r < 4; ++r) {
        float wval = exp2f(s[r] * SCALE2 - c);
        wbuf[wv][quad * 4 + r][cg * 16 + mcol] = f2bf(wval);
      }
    }
    // same-wave LDS RAW: in-order DS + compiler lgkmcnt handles this
    bf16x8 wa = *reinterpret_cast<const bf16x8*>(&wbuf[wv][mcol][quad * 8]);
    #pragma unroll
    for (int dt = 0; dt < 8; ++dt) {
      const unsigned short* Vp =
          Vbase + (size_t)(dt * 16 + mcol) * M_ + m0 + quad * 8;
      bf16x8 bfV = *reinterpret_cast<const bf16x8*>(Vp);
      o[dt] = __builtin_amdgcn_mfma_f32_16x16x32_bf16(wa, bfV, o[dt], 0, 0, 0);
    }
  }

  // epilogue: o[dt][r] = O[n0+quad*4+r][dt*16+mcol]
  #pragma unroll
  for (int dt = 0; dt < 8; ++dt)
    #pragma unroll
    for (int r = 0; r < 4; ++r)
      out[((size_t)b * N_ + n0 + quad * 4 + r) * D_ + dt * 16 + mcol] = o[dt][r];
}

extern "C" void kernel_launch(void* const* d_in, const int* in_sizes, int n_in,
                              void* d_out, int out_size, void* d_ws, size_t ws_size,
                              hipStream_t stream) {
  const float* Q = (const float*)d_in[0];
  const float* K = (const float*)d_in[1];
  const float* V = (const float*)d_in[2];
  float* out = (float*)d_out;

  const size_t elems = (size_t)B_ * N_ * D_;  // 8,388,608 per tensor
  unsigned short* Qb = (unsigned short*)d_ws;
  unsigned short* Kb = Qb + elems;
  unsigned short* Vt = Kb + elems;
  float* cmla = (float*)(Vt + elems);         // 32*2048 floats
  // total ws use: 3*16 MB + 256 KB ≈ 50.6 MB

  const int n4 = (int)(elems / 4);
  cvt_bf16_kernel<<<n4 / 256, 256, 0, stream>>>(Q, Qb, n4);
  cvt_bf16_kernel<<<n4 / 256, 256, 0, stream>>>(K, Kb, n4);
  transpose_v_kernel<<<dim3(M_ / 64, D_ / 64, B_), 256, 0, stream>>>(V, Vt);
  colstats_kernel<<<dim3(M_ / 64, B_), 256, 0, stream>>>(Qb, Kb, cmla);
  attn_out_kernel<<<dim3(N_ / 64, B_), 256, 0, stream>>>(Qb, Kb, Vt, cmla, out);
}

// Round 2
// 288.394 us; speedup vs baseline: 2.8362x; 2.8362x over previous
//
#include <hip/hip_runtime.h>
#include <hip/hip_bf16.h>

#define B_  32
#define N_  2048
#define M_  2048
#define D_  128

typedef __attribute__((ext_vector_type(4))) float f32x4;
typedef __attribute__((ext_vector_type(8))) short bf16x8;

// log2(e) / sqrt(128): softmax in exp2 domain; folded into Q's bf16 cast.
static constexpr float SCALE2 = 1.4426950408889634f / 11.313708498984761f;

__device__ __forceinline__ unsigned short f2bf(float x) {
  union { float f; unsigned u; } c; c.f = x;
  unsigned u = c.u;
  return (unsigned short)((u + 0x7FFFu + ((u >> 16) & 1u)) >> 16);  // RNE
}

// async global->LDS, 16B per lane; LDS dest must be wave-uniform base + lane*16
__device__ __forceinline__ void gl2lds16(const void* gp, void* lp) {
  __builtin_amdgcn_global_load_lds(
      (const __attribute__((address_space(1))) unsigned int*)gp,
      (__attribute__((address_space(3))) unsigned int*)lp, 16, 0, 0);
}

// ---------- prep: fp32 -> bf16 elementwise with scale (Q gets SCALE2, K gets 1) ----------
__global__ __launch_bounds__(256) void cvt_bf16_kernel(
    const float* __restrict__ src, unsigned short* __restrict__ dst, int n4, float scale) {
  int i = blockIdx.x * blockDim.x + threadIdx.x;
  if (i >= n4) return;
  const float4 v = reinterpret_cast<const float4*>(src)[i];
  ushort4 o;
  o.x = f2bf(v.x * scale); o.y = f2bf(v.y * scale);
  o.z = f2bf(v.z * scale); o.w = f2bf(v.w * scale);
  reinterpret_cast<ushort4*>(dst)[i] = o;
}

// ---------- pass 1: vscale[m] = 1 / sum_n 2^(s2[n,m]) ----------
// grid (M/128, B), 4 waves; wave owns 32 m-cols (K-frags in regs), Q staged in LDS.
__global__ __launch_bounds__(256, 4) void colstats_kernel(
    const unsigned short* __restrict__ Qb, const unsigned short* __restrict__ Kb,
    float* __restrict__ vscale) {
  const int b    = blockIdx.y;
  const int wv   = threadIdx.x >> 6;
  const int lane = threadIdx.x & 63;
  const int mcol = lane & 15;
  const int quad = lane >> 4;
  const int mw   = blockIdx.x * 128 + wv * 32;

  // qbuf: rows n (256B), 16B chunks xor-swizzled: chunk c stored at c ^ (n&15)
  __shared__ unsigned short qbuf[64 * 128];  // 16 KB

  // K fragments (B-operand: B[m=lane&15][k=quad*8+j]) for 2 col-groups
  bf16x8 kf[2][4];
  #pragma unroll
  for (int cg = 0; cg < 2; ++cg) {
    const unsigned short* Kr = Kb + ((size_t)b * M_ + mw + cg * 16 + mcol) * D_ + quad * 8;
    #pragma unroll
    for (int kc = 0; kc < 4; ++kc)
      kf[cg][kc] = *reinterpret_cast<const bf16x8*>(Kr + kc * 32);
  }

  const unsigned short* Qbb = Qb + (size_t)b * N_ * D_;
  float psum0 = 0.f, psum1 = 0.f;

  for (int nt = 0; nt < N_; nt += 64) {
    __syncthreads();
    #pragma unroll
    for (int i = 0; i < 4; ++i) {
      int s = (wv * 4 + i) * 64 + lane;          // 16B slot 0..1023
      int nloc = s >> 4, cp = s & 15, c = cp ^ (nloc & 15);
      gl2lds16(Qbb + (size_t)(nt + nloc) * D_ + c * 8,
               (char*)qbuf + (size_t)s * 16);
    }
    __syncthreads();
    #pragma unroll
    for (int ng = 0; ng < 4; ++ng) {
      const int n_l = ng * 16 + mcol;            // A-row = lane&15
      f32x4 a0 = {0.f,0.f,0.f,0.f}, a1 = {0.f,0.f,0.f,0.f};
      #pragma unroll
      for (int kc = 0; kc < 4; ++kc) {
        int c = (kc * 4 + quad) ^ (n_l & 15);
        bf16x8 af = *reinterpret_cast<const bf16x8*>(qbuf + n_l * 128 + c * 8);
        a0 = __builtin_amdgcn_mfma_f32_16x16x32_bf16(af, kf[0][kc], a0, 0, 0, 0);
        a1 = __builtin_amdgcn_mfma_f32_16x16x32_bf16(af, kf[1][kc], a1, 0, 0, 0);
      }
      #pragma unroll
      for (int r = 0; r < 4; ++r) {
        psum0 += exp2f(a0[r] - 16.f);
        psum1 += exp2f(a1[r] - 16.f);
      }
    }
  }
  // reduce partial column sums across quads (columns live on lane&15)
  psum0 += __shfl_xor(psum0, 16); psum0 += __shfl_xor(psum0, 32);
  psum1 += __shfl_xor(psum1, 16); psum1 += __shfl_xor(psum1, 32);
  if (quad == 0) {
    vscale[(size_t)b * M_ + mw + mcol]      = 0x1p-16f / psum0;
    vscale[(size_t)b * M_ + mw + 16 + mcol] = 0x1p-16f / psum1;
  }
}

// ---------- prep: V (b,m,d) fp32 -> Vt (b,d,m) bf16, folding vscale[m] ----------
__global__ __launch_bounds__(256) void transpose_v_kernel(
    const float* __restrict__ V, const float* __restrict__ vscale,
    unsigned short* __restrict__ Vt) {
  const int b = blockIdx.z;
  const int m0 = blockIdx.x * 64;
  const int d0 = blockIdx.y * 64;
  __shared__ float t[64][65];
  const int tid = threadIdx.x;
  const int r = tid >> 2;   // 0..63
  const int c = tid & 3;    // 0..3
  const float* src = V + ((size_t)b * M_ + (m0 + r)) * D_ + d0 + c * 16;
  #pragma unroll
  for (int i = 0; i < 4; ++i) {
    float4 v = reinterpret_cast<const float4*>(src)[i];
    t[r][c * 16 + i * 4 + 0] = v.x;
    t[r][c * 16 + i * 4 + 1] = v.y;
    t[r][c * 16 + i * 4 + 2] = v.z;
    t[r][c * 16 + i * 4 + 3] = v.w;
  }
  __syncthreads();
  const float* vs = vscale + (size_t)b * M_ + m0 + c * 16;
  ushort4 ob[4];
  #pragma unroll
  for (int i = 0; i < 4; ++i) {
    float4 s4 = reinterpret_cast<const float4*>(vs)[i];
    ob[i].x = f2bf(t[c * 16 + i * 4 + 0][r] * s4.x);
    ob[i].y = f2bf(t[c * 16 + i * 4 + 1][r] * s4.y);
    ob[i].z = f2bf(t[c * 16 + i * 4 + 2][r] * s4.z);
    ob[i].w = f2bf(t[c * 16 + i * 4 + 3][r] * s4.w);
  }
  ushort4* dst = reinterpret_cast<ushort4*>(
      Vt + ((size_t)b * D_ + d0 + r) * M_ + m0 + c * 16);
  #pragma unroll
  for (int i = 0; i < 4; ++i) dst[i] = ob[i];
}

// ---------- pass 2: O[n,d] = sum_m 2^(s2[n,m]) * V'[d,m] ----------
// grid (N/128, B), 4 waves x 32n; m-chunks of 64 staged in LDS (K 16KB + Vt 16KB).
__global__ __launch_bounds__(256, 2) void attn_out_kernel(
    const unsigned short* __restrict__ Qb, const unsigned short* __restrict__ Kb,
    const unsigned short* __restrict__ Vt, float* __restrict__ out) {
  const int b    = blockIdx.y;
  const int wv   = threadIdx.x >> 6;
  const int lane = threadIdx.x & 63;
  const int mcol = lane & 15;
  const int quad = lane >> 4;
  const int nw   = blockIdx.x * 128 + wv * 32;

  __shared__ unsigned short kbuf[64 * 128];    // [m][d-chunk swizzled], 16 KB
  __shared__ unsigned short vbuf[128 * 64];    // [d][m-chunk swizzled], 16 KB
  __shared__ unsigned short pbuf[4][32 * 72];  // per-wave [n][m], 144B stride, 18 KB

  // Q fragments (A: A[n=lane&15][k=quad*8+j]) for 2 row-groups — loop invariant
  bf16x8 qf[2][4];
  #pragma unroll
  for (int rg = 0; rg < 2; ++rg) {
    const unsigned short* Qr =
        Qb + ((size_t)b * N_ + nw + rg * 16 + mcol) * D_ + quad * 8;
    #pragma unroll
    for (int kc = 0; kc < 4; ++kc)
      qf[rg][kc] = *reinterpret_cast<const bf16x8*>(Qr + kc * 32);
  }

  f32x4 o[2][8];
  #pragma unroll
  for (int rg = 0; rg < 2; ++rg)
    #pragma unroll
    for (int dt = 0; dt < 8; ++dt) o[rg][dt] = (f32x4){0.f,0.f,0.f,0.f};

  const unsigned short* Kbb = Kb + (size_t)b * M_ * D_;
  const unsigned short* Vbb = Vt + (size_t)b * D_ * M_;
  unsigned short* pw = pbuf[wv];

  for (int m0 = 0; m0 < M_; m0 += 64) {
    __syncthreads();   // everyone done reading previous K/V tiles
    #pragma unroll
    for (int i = 0; i < 4; ++i) {
      int s = (wv * 4 + i) * 64 + lane;          // 16B slot 0..1023
      // K tile: rows m (256B), chunk c stored at position c ^ (m&15)
      int mloc = s >> 4, ck = (s & 15) ^ (mloc & 15);
      gl2lds16(Kbb + (size_t)(m0 + mloc) * D_ + ck * 8,
               (char*)kbuf + (size_t)s * 16);
      // V tile: rows d (128B), chunk c stored at position c ^ (d&7)
      int dloc = s >> 3, cv = (s & 7) ^ (dloc & 7);
      gl2lds16(Vbb + (size_t)dloc * M_ + m0 + cv * 8,
               (char*)vbuf + (size_t)s * 16);
    }
    __syncthreads();   // staging visible

    // QK: S tile 32n x 64m per wave; P -> per-wave LDS (bf16)
    #pragma unroll
    for (int cg = 0; cg < 4; ++cg) {
      const int m_l = cg * 16 + mcol;
      f32x4 s0 = {0.f,0.f,0.f,0.f}, s1 = {0.f,0.f,0.f,0.f};
      #pragma unroll
      for (int kc = 0; kc < 4; ++kc) {
        int c = (kc * 4 + quad) ^ (m_l & 15);
        bf16x8 kfr = *reinterpret_cast<const bf16x8*>(kbuf + m_l * 128 + c * 8);
        s0 = __builtin_amdgcn_mfma_f32_16x16x32_bf16(qf[0][kc], kfr, s0, 0, 0, 0);
        s1 = __builtin_amdgcn_mfma_f32_16x16x32_bf16(qf[1][kc], kfr, s1, 0, 0, 0);
      }
      #pragma unroll
      for (int r = 0; r < 4; ++r) {
        pw[(quad * 4 + r) * 72 + m_l]        = f2bf(exp2f(s0[r]));
        pw[(16 + quad * 4 + r) * 72 + m_l]   = f2bf(exp2f(s1[r]));
      }
    }
    // P A-fragments (same-wave LDS RAW; in-order DS + lgkmcnt)
    bf16x8 pa[2][2];
    #pragma unroll
    for (int rg = 0; rg < 2; ++rg)
      #pragma unroll
      for (int kc2 = 0; kc2 < 2; ++kc2)
        pa[rg][kc2] = *reinterpret_cast<const bf16x8*>(
            pw + (rg * 16 + mcol) * 72 + kc2 * 32 + quad * 8);
    // PV: o += P * V'
    #pragma unroll
    for (int dt = 0; dt < 8; ++dt) {
      const int d = dt * 16 + mcol;
      #pragma unroll
      for (int kc2 = 0; kc2 < 2; ++kc2) {
        int cv = (kc2 * 4 + quad) ^ (d & 7);
        bf16x8 vfr = *reinterpret_cast<const bf16x8*>(vbuf + d * 64 + cv * 8);
        o[0][dt] = __builtin_amdgcn_mfma_f32_16x16x32_bf16(pa[0][kc2], vfr, o[0][dt], 0, 0, 0);
        o[1][dt] = __builtin_amdgcn_mfma_f32_16x16x32_bf16(pa[1][kc2], vfr, o[1][dt], 0, 0, 0);
      }
    }
  }

  // epilogue: o[rg][dt][r] = O[nw + rg*16 + quad*4 + r][dt*16 + mcol]
  #pragma unroll
  for (int rg = 0; rg < 2; ++rg)
    #pragma unroll
    for (int dt = 0; dt < 8; ++dt)
      #pragma unroll
      for (int r = 0; r < 4; ++r)
        out[((size_t)b * N_ + nw + rg * 16 + quad * 4 + r) * D_ + dt * 16 + mcol] =
            o[rg][dt][r];
}

extern "C" void kernel_launch(void* const* d_in, const int* in_sizes, int n_in,
                              void* d_out, int out_size, void* d_ws, size_t ws_size,
                              hipStream_t stream) {
  const float* Q = (const float*)d_in[0];
  const float* K = (const float*)d_in[1];
  const float* V = (const float*)d_in[2];
  float* out = (float*)d_out;

  const size_t elems = (size_t)B_ * N_ * D_;  // 8,388,608 per tensor
  unsigned short* Qb = (unsigned short*)d_ws;
  unsigned short* Kb = Qb + elems;
  unsigned short* Vt = Kb + elems;
  float* vscale = (float*)(Vt + elems);       // 32*2048 floats
  // total ws use: 3*16 MB + 256 KB ~= 50.6 MB

  const int n4 = (int)(elems / 4);
  cvt_bf16_kernel<<<n4 / 256, 256, 0, stream>>>(Q, Qb, n4, SCALE2);
  cvt_bf16_kernel<<<n4 / 256, 256, 0, stream>>>(K, Kb, n4, 1.0f);
  colstats_kernel<<<dim3(M_ / 128, B_), 256, 0, stream>>>(Qb, Kb, vscale);
  transpose_v_kernel<<<dim3(M_ / 64, D_ / 64, B_), 256, 0, stream>>>(V, vscale, Vt);
  attn_out_kernel<<<dim3(N_ / 128, B_), 256, 0, stream>>>(Qb, Kb, Vt, out);
}

// Round 4
// 286.068 us; speedup vs baseline: 2.8593x; 1.0081x over previous
//
#include <hip/hip_runtime.h>
#include <hip/hip_bf16.h>

#define B_  32
#define N_  2048
#define M_  2048
#define D_  128

typedef __attribute__((ext_vector_type(4))) float f32x4;
typedef __attribute__((ext_vector_type(8))) short bf16x8;

// log2(e) / sqrt(128): softmax in exp2 domain; folded into Q's bf16 cast.
static constexpr float SCALE2 = 1.4426950408889634f / 11.313708498984761f;

__device__ __forceinline__ unsigned short f2bf(float x) {
  union { float f; unsigned u; } c; c.f = x;
  unsigned u = c.u;
  return (unsigned short)((u + 0x7FFFu + ((u >> 16) & 1u)) >> 16);  // RNE
}

__device__ __forceinline__ unsigned pk2bf(float a, float b) {
  float2 f2; f2.x = a; f2.y = b;
  __hip_bfloat162 h = __float22bfloat162_rn(f2);   // v_cvt_pk_bf16_f32 on gfx950
  union { __hip_bfloat162 h; unsigned u; } c; c.h = h;
  return c.u;
}

// async global->LDS, 16B per lane; LDS dest = wave-uniform base + lane*16
__device__ __forceinline__ void gl2lds16(const void* gp, void* lp) {
  __builtin_amdgcn_global_load_lds(
      (const __attribute__((address_space(1))) unsigned int*)gp,
      (__attribute__((address_space(3))) unsigned int*)lp, 16, 0, 0);
}

// ---------- prep: fp32 -> bf16 for Q (scale=SCALE2) and K (scale=1), one dispatch ----------
__global__ __launch_bounds__(256) void cvt_qk_kernel(
    const float* __restrict__ Q, const float* __restrict__ K,
    unsigned short* __restrict__ Qb, unsigned short* __restrict__ Kb, int n4) {
  int i = blockIdx.x * 256 + threadIdx.x;
  if (i >= n4) return;
  const float* src = blockIdx.y ? K : Q;
  unsigned short* dst = blockIdx.y ? Kb : Qb;
  const float sc = blockIdx.y ? 1.0f : SCALE2;
  const float4 v = reinterpret_cast<const float4*>(src)[i];
  ushort4 o;
  o.x = f2bf(v.x * sc); o.y = f2bf(v.y * sc);
  o.z = f2bf(v.z * sc); o.w = f2bf(v.w * sc);
  reinterpret_cast<ushort4*>(dst)[i] = o;
}

// ---------- pass 1: vscale[m] = 2^-16 / sum_n 2^(s2[n,m]-16) ----------
// grid (M/64, B), 4 waves; wave owns 16 m (K-frags in regs); Q staged in LDS,
// single-buffer two-barrier (replay-proven sync discipline).
__global__ __launch_bounds__(256, 4) void colstats_kernel(
    const unsigned short* __restrict__ Qb, const unsigned short* __restrict__ Kb,
    float* __restrict__ vscale) {
  const int b    = blockIdx.y;
  const int wv   = threadIdx.x >> 6;
  const int lane = threadIdx.x & 63;
  const int l15  = lane & 15;
  const int quad = lane >> 4;
  const int mw   = blockIdx.x * 64 + wv * 16;

  // qbuf rows n (256B = 16 chunks of 16B), chunk c stored at position c ^ (n&15)
  __shared__ unsigned short qbuf[64 * 128];   // 16 KB

  bf16x8 kf[4];  // B-operand: B[col=m=l15][k=quad*8+j]
  {
    const unsigned short* Kr = Kb + ((size_t)b * M_ + mw + l15) * D_ + quad * 8;
    #pragma unroll
    for (int kc = 0; kc < 4; ++kc)
      kf[kc] = *reinterpret_cast<const bf16x8*>(Kr + kc * 32);
  }

  const unsigned short* Qbb = Qb + (size_t)b * N_ * D_;
  float psum = 0.f;

  for (int nt = 0; nt < N_; nt += 64) {
    __syncthreads();                             // previous-tile reads done
    #pragma unroll
    for (int i = 0; i < 4; ++i) {
      int s = (wv * 4 + i) * 64 + lane;          // 16B slot 0..1023
      int nloc = s >> 4, c = (s & 15) ^ (nloc & 15);
      gl2lds16(Qbb + (size_t)(nt + nloc) * D_ + c * 8,
               (char*)qbuf + (size_t)s * 16);
    }
    __syncthreads();                             // staging visible
    #pragma unroll
    for (int ng = 0; ng < 4; ++ng) {
      const int n_l = ng * 16 + l15;
      f32x4 acc = {0.f, 0.f, 0.f, 0.f};
      #pragma unroll
      for (int kc = 0; kc < 4; ++kc) {
        int c = (kc * 4 + quad) ^ (n_l & 15);
        bf16x8 af = *reinterpret_cast<const bf16x8*>(qbuf + n_l * 128 + c * 8);
        acc = __builtin_amdgcn_mfma_f32_16x16x32_bf16(af, kf[kc], acc, 0, 0, 0);
      }
      psum += exp2f(acc[0] - 16.f) + exp2f(acc[1] - 16.f) +
              exp2f(acc[2] - 16.f) + exp2f(acc[3] - 16.f);
    }
  }
  psum += __shfl_xor(psum, 16);
  psum += __shfl_xor(psum, 32);
  if (quad == 0) vscale[(size_t)b * M_ + mw + l15] = 0x1p-16f / psum;
}

// ---------- prep: V (b,m,d) fp32 -> Vt (b,d,m) bf16, folding vscale[m] ----------
__global__ __launch_bounds__(256) void transpose_v_kernel(
    const float* __restrict__ V, const float* __restrict__ vscale,
    unsigned short* __restrict__ Vt) {
  const int b = blockIdx.z;
  const int m0 = blockIdx.x * 64;
  const int d0 = blockIdx.y * 64;
  __shared__ float t[64][65];
  const int tid = threadIdx.x;
  const int r = tid >> 2;   // 0..63
  const int c = tid & 3;    // 0..3
  const float* src = V + ((size_t)b * M_ + (m0 + r)) * D_ + d0 + c * 16;
  #pragma unroll
  for (int i = 0; i < 4; ++i) {
    float4 v = reinterpret_cast<const float4*>(src)[i];
    t[r][c * 16 + i * 4 + 0] = v.x;
    t[r][c * 16 + i * 4 + 1] = v.y;
    t[r][c * 16 + i * 4 + 2] = v.z;
    t[r][c * 16 + i * 4 + 3] = v.w;
  }
  __syncthreads();
  const float* vs = vscale + (size_t)b * M_ + m0 + c * 16;
  ushort4 ob[4];
  #pragma unroll
  for (int i = 0; i < 4; ++i) {
    float4 s4 = reinterpret_cast<const float4*>(vs)[i];
    ob[i].x = f2bf(t[c * 16 + i * 4 + 0][r] * s4.x);
    ob[i].y = f2bf(t[c * 16 + i * 4 + 1][r] * s4.y);
    ob[i].z = f2bf(t[c * 16 + i * 4 + 2][r] * s4.z);
    ob[i].w = f2bf(t[c * 16 + i * 4 + 3][r] * s4.w);
  }
  ushort4* dst = reinterpret_cast<ushort4*>(
      Vt + ((size_t)b * D_ + d0 + r) * M_ + m0 + c * 16);
  #pragma unroll
  for (int i = 0; i < 4; ++i) dst[i] = ob[i];
}

// ---------- pass 2: O[n,d] = sum_m 2^(s2[n,m]) * V'[m,d] ----------
// grid (N/64, B) = 1024 blocks (4/CU); 4 waves x 16n; m-chunks of 32,
// single-buffer two-barrier staging (replay-proven). QK computed TRANSPOSED
// (A=K, B=Q) so each lane's 4 acc regs are consecutive m: P store = packed
// ds_write_b64 instead of 4 scalar u16 stores.
__global__ __launch_bounds__(256, 4) void attn_out_kernel(
    const unsigned short* __restrict__ Qb, const unsigned short* __restrict__ Kb,
    const unsigned short* __restrict__ Vt, float* __restrict__ out) {
  const int b    = blockIdx.y;
  const int wv   = threadIdx.x >> 6;
  const int lane = threadIdx.x & 63;
  const int l15  = lane & 15;
  const int quad = lane >> 4;
  const int nw   = blockIdx.x * 64 + wv * 16;

  __shared__ unsigned short kbuf[32 * 128];  // 8 KB, rows m (256B, 16 chunks)
  __shared__ unsigned short vbuf[128 * 32];  // 8 KB, rows d (64B, 4 chunks)
  __shared__ unsigned short pbuf[4][16 * 40]; // per-wave P^T: [n][m], stride 40 u16

  // Q fragments, B-operand: B[col=n=l15][k=quad*8+j] — loop invariant
  bf16x8 qf[4];
  {
    const unsigned short* Qr = Qb + ((size_t)b * N_ + nw + l15) * D_ + quad * 8;
    #pragma unroll
    for (int kc = 0; kc < 4; ++kc)
      qf[kc] = *reinterpret_cast<const bf16x8*>(Qr + kc * 32);
  }

  f32x4 o[8];
  #pragma unroll
  for (int dt = 0; dt < 8; ++dt) o[dt] = (f32x4){0.f, 0.f, 0.f, 0.f};

  const unsigned short* Kbb = Kb + (size_t)b * M_ * D_;
  const unsigned short* Vbb = Vt + (size_t)b * D_ * M_;
  unsigned short* pw = pbuf[wv];

  for (int m0 = 0; m0 < M_; m0 += 32) {
    __syncthreads();                           // previous-chunk reads done
    #pragma unroll
    for (int i = 0; i < 2; ++i) {
      int s = (wv * 2 + i) * 64 + lane;        // 16B slot 0..511
      // K tile: slot s holds row m=s>>4, chunk ((s&15) ^ (m&15))
      int mloc = s >> 4, ck = (s & 15) ^ (mloc & 15);
      gl2lds16(Kbb + (size_t)(m0 + mloc) * D_ + ck * 8,
               (char*)kbuf + (size_t)s * 16);
      // V tile: slot s holds row d=s>>2, chunk ((s&3) ^ ((d>>1)&3))
      int dloc = s >> 2, cv = (s & 3) ^ ((dloc >> 1) & 3);
      gl2lds16(Vbb + (size_t)dloc * M_ + m0 + cv * 8,
               (char*)vbuf + (size_t)s * 16);
    }
    __syncthreads();                           // staging visible

    // QK^T: D[m][n]; lane holds m = cg*16 + quad*4 + r, n = nw + l15
    #pragma unroll
    for (int cg = 0; cg < 2; ++cg) {
      const int m_l = cg * 16 + l15;
      f32x4 s = {0.f, 0.f, 0.f, 0.f};
      #pragma unroll
      for (int kc = 0; kc < 4; ++kc) {
        int c = (kc * 4 + quad) ^ l15;         // position swizzle (m_l&15 == l15)
        bf16x8 kfr = *reinterpret_cast<const bf16x8*>(kbuf + m_l * 128 + c * 8);
        s = __builtin_amdgcn_mfma_f32_16x16x32_bf16(kfr, qf[kc], s, 0, 0, 0);
      }
      uint2 w;
      w.x = pk2bf(exp2f(s[0]), exp2f(s[1]));
      w.y = pk2bf(exp2f(s[2]), exp2f(s[3]));
      *reinterpret_cast<uint2*>(pw + l15 * 40 + cg * 16 + quad * 4) = w;
    }
    // P A-fragment: A[row=n=l15][k=m=quad*8+j] (same-wave LDS RAW; lgkmcnt ordered)
    bf16x8 pa = *reinterpret_cast<const bf16x8*>(pw + l15 * 40 + quad * 8);
    // PV: o[n][d] += P * V'
    #pragma unroll
    for (int dt = 0; dt < 8; ++dt) {
      const int d = dt * 16 + l15;
      int slot = d * 4 + (quad ^ ((d >> 1) & 3));
      bf16x8 vfr = *reinterpret_cast<const bf16x8*>((const char*)vbuf + (size_t)slot * 16);
      o[dt] = __builtin_amdgcn_mfma_f32_16x16x32_bf16(pa, vfr, o[dt], 0, 0, 0);
    }
  }

  // epilogue: o[dt][r] = O[nw + quad*4 + r][dt*16 + l15]
  #pragma unroll
  for (int dt = 0; dt < 8; ++dt)
    #pragma unroll
    for (int r = 0; r < 4; ++r)
      out[((size_t)b * N_ + nw + quad * 4 + r) * D_ + dt * 16 + l15] = o[dt][r];
}

extern "C" void kernel_launch(void* const* d_in, const int* in_sizes, int n_in,
                              void* d_out, int out_size, void* d_ws, size_t ws_size,
                              hipStream_t stream) {
  const float* Q = (const float*)d_in[0];
  const float* K = (const float*)d_in[1];
  const float* V = (const float*)d_in[2];
  float* out = (float*)d_out;

  const size_t elems = (size_t)B_ * N_ * D_;  // 8,388,608 per tensor
  unsigned short* Qb = (unsigned short*)d_ws;
  unsigned short* Kb = Qb + elems;
  unsigned short* Vt = Kb + elems;
  float* vscale = (float*)(Vt + elems);       // 32*2048 floats
  // total ws use: 3*16 MB + 256 KB ~= 50.6 MB

  const int n4 = (int)(elems / 4);
  cvt_qk_kernel<<<dim3(n4 / 256, 2), 256, 0, stream>>>(Q, K, Qb, Kb, n4);
  colstats_kernel<<<dim3(M_ / 64, B_), 256, 0, stream>>>(Qb, Kb, vscale);
  transpose_v_kernel<<<dim3(M_ / 64, D_ / 64, B_), 256, 0, stream>>>(V, vscale, Vt);
  attn_out_kernel<<<dim3(N_ / 64, B_), 256, 0, stream>>>(Qb, Kb, Vt, out);
}